// Round 7
// baseline (337.441 us; speedup 1.0000x reference)
//
#include <hip/hip_runtime.h>
#include <hip/hip_bf16.h>
#include <cstdint>
#include <cstddef>

// RGCN layer, fused v3:
//   out[n] = (sum_r h_r[n]@W[r] + x[n]@W0) / max(deg,1)
// k_fused: 32 nodes/block, 16 waves, LDS A[32][1160] bf16 (pad 2320B/row).
// Phase 1 = round-5 gather (CSR by dst, wave-uniform relation switch, bf16),
// 2 nodes/wave, written to padded LDS. Phase 2 = 8 waves x 36-step MFMA vs
// L2-resident Wb. 74.2 KB LDS -> 2 blocks/CU so gather of one block overlaps
// MFMA/barrier of the other. Preprocessing: 5 dispatches total.

#define NDIM 128
#define NREL 8
#define KCAT 1152        // 9*128
#define ROWP 2320        // 2304 data bytes + 16 pad (stride = 4 banks mod 32)

typedef __attribute__((ext_vector_type(8))) short bf16x8;
typedef __attribute__((ext_vector_type(4))) float f32x4;
typedef unsigned int uint32;

__device__ __forceinline__ short f2bf(float f){
  __hip_bfloat16 h = __float2bfloat16(f);
  return *reinterpret_cast<short*>(&h);
}
__device__ __forceinline__ float bfl(uint32 v){ return __uint_as_float(v << 16); }
__device__ __forceinline__ float bfh(uint32 v){ return __uint_as_float(v & 0xFFFF0000u); }

// ---------- K1: x->bf16, W->Wb (transposed bf16), zero deg, detect (merged) ----------
__global__ void k_prep(const float* __restrict__ x, uint32* __restrict__ xb, int n4, int xblocks,
                       const float* __restrict__ W, const float* __restrict__ W0,
                       short* __restrict__ Wb, int wblocks,
                       const int* __restrict__ ei, int* flag, int* deg, int N){
  int b = blockIdx.x;
  if (b < xblocks){
    int i = b * 256 + threadIdx.x;
    if (i >= n4) return;
    float4 f = ((const float4*)x)[i];
    uint32 lo = ((uint32)(unsigned short)f2bf(f.x)) | (((uint32)(unsigned short)f2bf(f.y)) << 16);
    uint32 hi = ((uint32)(unsigned short)f2bf(f.z)) | (((uint32)(unsigned short)f2bf(f.w)) << 16);
    ((uint2*)xb)[i] = make_uint2(lo, hi);
  } else if (b < xblocks + wblocks){
    int i = (b - xblocks) * 256 + threadIdx.x;
    if (i >= NDIM * KCAT) return;
    int j  = i / KCAT;
    int t  = i - j * KCAT;
    int r  = t >> 7;
    int kd = t & 127;
    float v = (r < NREL) ? W[(((size_t)r * NDIM + kd) << 7) + j] : W0[((size_t)kd << 7) + j];
    Wb[i] = f2bf(v);
  } else {
    int bb = b - xblocks - wblocks;
    int i = bb * 256 + threadIdx.x;
    if (i < N) deg[i] = 0;
    if (bb == 0 && threadIdx.x < 64){
      int v = ei[2 * threadIdx.x + 1];
      unsigned long long m = __ballot(v == 0);
      if (threadIdx.x == 0) flag[0] = (m == ~0ull) ? 1 : 0;
    }
  }
}

// ---------- K2: normalize edges + degree histogram ----------
__global__ void k_norm(const int* ei, const int* et, const int* __restrict__ flag,
                       int* st, int* darr, int* deg, int E){
  int e = blockIdx.x * 256 + threadIdx.x;
  if (e >= E) return;
  int is64 = flag[0];
  int s, d, t;
  if (is64){ s = ei[2*e]; d = ei[2*(E + e)]; t = et[2*e]; }
  else     { s = ei[e];   d = ei[E + e];     t = et[e];   }
  st[e]   = s | (t << 20);
  darr[e] = d;
  atomicAdd(&deg[d], 1);
}

// ---------- K3: single-block exclusive scan -> rs, cursor ----------
__global__ __launch_bounds__(1024) void k_scan1(const int* __restrict__ deg,
                                                int* rs, int* cursor, int N, int E){
  __shared__ int part[1024];
  int t = threadIdx.x;
  int per = (N + 1023) / 1024;
  int b0 = t * per;
  int s = 0;
  for (int i = 0; i < per; ++i){
    int idx = b0 + i;
    if (idx < N) s += deg[idx];
  }
  part[t] = s; __syncthreads();
  for (int off = 1; off < 1024; off <<= 1){
    int v = 0; if (t >= off) v = part[t - off];
    __syncthreads(); part[t] += v; __syncthreads();
  }
  int run = part[t] - s;
  for (int i = 0; i < per; ++i){
    int idx = b0 + i;
    if (idx < N){
      rs[idx] = run; cursor[idx] = run;
      run += deg[idx];
    }
  }
  if (t == 1023) rs[N] = E;
}

// ---------- K4: scatter edges into CSR buckets ----------
__global__ void k_scatter(const int* st, const int* darr, int* cursor, int* esort, int E){
  int e = blockIdx.x * 256 + threadIdx.x;
  if (e >= E) return;
  int pos = atomicAdd(&cursor[darr[e]], 1);
  esort[pos] = st[e];
}

// ---------- K5: fused gather -> padded LDS -> MFMA -> out ----------
__global__ __launch_bounds__(1024) void k_fused(
    const uint32* __restrict__ xb,    // [N][64] bf16x2
    const int* __restrict__ rs,       // [N+1]
    const int* __restrict__ esort,    // [E] src|type<<20, CSR by dst
    const short* __restrict__ wb,     // [128][1152] bf16
    float* __restrict__ out, int N)
{
  __shared__ char smem[32 * ROWP];    // 74240 B -> 2 blocks/CU
  const int lane = threadIdx.x & 63;
  const int wid  = threadIdx.x >> 6;  // 0..15
  const int n0   = blockIdx.x * 32;

  // ---- Phase 1: gather, 2 nodes per wave, round-5 inner loop ----
  for (int half = 0; half < 2; ++half){
    const int row  = wid * 2 + half;  // 0..31
    const int node = n0 + row;
    float2 acc[NREL];
    #pragma unroll
    for (int r = 0; r < NREL; ++r){ acc[r].x = 0.f; acc[r].y = 0.f; }
    int beg = 0, end = 0;
    if (node < N){ beg = rs[node]; end = rs[node + 1]; }

    int i = beg;
    for (; i + 3 < end; i += 4){
      int p0 = esort[i], p1 = esort[i+1], p2 = esort[i+2], p3 = esort[i+3];
      uint32 v0 = xb[(size_t)(p0 & 0xFFFFF) * 64 + lane];
      uint32 v1 = xb[(size_t)(p1 & 0xFFFFF) * 64 + lane];
      uint32 v2 = xb[(size_t)(p2 & 0xFFFFF) * 64 + lane];
      uint32 v3 = xb[(size_t)(p3 & 0xFFFFF) * 64 + lane];
      switch (p0 >> 20){
        case 0: acc[0].x+=bfl(v0); acc[0].y+=bfh(v0); break; case 1: acc[1].x+=bfl(v0); acc[1].y+=bfh(v0); break;
        case 2: acc[2].x+=bfl(v0); acc[2].y+=bfh(v0); break; case 3: acc[3].x+=bfl(v0); acc[3].y+=bfh(v0); break;
        case 4: acc[4].x+=bfl(v0); acc[4].y+=bfh(v0); break; case 5: acc[5].x+=bfl(v0); acc[5].y+=bfh(v0); break;
        case 6: acc[6].x+=bfl(v0); acc[6].y+=bfh(v0); break; case 7: acc[7].x+=bfl(v0); acc[7].y+=bfh(v0); break;
      }
      switch (p1 >> 20){
        case 0: acc[0].x+=bfl(v1); acc[0].y+=bfh(v1); break; case 1: acc[1].x+=bfl(v1); acc[1].y+=bfh(v1); break;
        case 2: acc[2].x+=bfl(v1); acc[2].y+=bfh(v1); break; case 3: acc[3].x+=bfl(v1); acc[3].y+=bfh(v1); break;
        case 4: acc[4].x+=bfl(v1); acc[4].y+=bfh(v1); break; case 5: acc[5].x+=bfl(v1); acc[5].y+=bfh(v1); break;
        case 6: acc[6].x+=bfl(v1); acc[6].y+=bfh(v1); break; case 7: acc[7].x+=bfl(v1); acc[7].y+=bfh(v1); break;
      }
      switch (p2 >> 20){
        case 0: acc[0].x+=bfl(v2); acc[0].y+=bfh(v2); break; case 1: acc[1].x+=bfl(v2); acc[1].y+=bfh(v2); break;
        case 2: acc[2].x+=bfl(v2); acc[2].y+=bfh(v2); break; case 3: acc[3].x+=bfl(v2); acc[3].y+=bfh(v2); break;
        case 4: acc[4].x+=bfl(v2); acc[4].y+=bfh(v2); break; case 5: acc[5].x+=bfl(v2); acc[5].y+=bfh(v2); break;
        case 6: acc[6].x+=bfl(v2); acc[6].y+=bfh(v2); break; case 7: acc[7].x+=bfl(v2); acc[7].y+=bfh(v2); break;
      }
      switch (p3 >> 20){
        case 0: acc[0].x+=bfl(v3); acc[0].y+=bfh(v3); break; case 1: acc[1].x+=bfl(v3); acc[1].y+=bfh(v3); break;
        case 2: acc[2].x+=bfl(v3); acc[2].y+=bfh(v3); break; case 3: acc[3].x+=bfl(v3); acc[3].y+=bfh(v3); break;
        case 4: acc[4].x+=bfl(v3); acc[4].y+=bfh(v3); break; case 5: acc[5].x+=bfl(v3); acc[5].y+=bfh(v3); break;
        case 6: acc[6].x+=bfl(v3); acc[6].y+=bfh(v3); break; case 7: acc[7].x+=bfl(v3); acc[7].y+=bfh(v3); break;
      }
    }
    for (; i < end; ++i){
      int p = esort[i];
      uint32 v = xb[(size_t)(p & 0xFFFFF) * 64 + lane];
      switch (p >> 20){
        case 0: acc[0].x+=bfl(v); acc[0].y+=bfh(v); break; case 1: acc[1].x+=bfl(v); acc[1].y+=bfh(v); break;
        case 2: acc[2].x+=bfl(v); acc[2].y+=bfh(v); break; case 3: acc[3].x+=bfl(v); acc[3].y+=bfh(v); break;
        case 4: acc[4].x+=bfl(v); acc[4].y+=bfh(v); break; case 5: acc[5].x+=bfl(v); acc[5].y+=bfh(v); break;
        case 6: acc[6].x+=bfl(v); acc[6].y+=bfh(v); break; case 7: acc[7].x+=bfl(v); acc[7].y+=bfh(v); break;
      }
    }

    char* rowp = smem + row * ROWP;
    #pragma unroll
    for (int r = 0; r < NREL; ++r){
      __hip_bfloat162 pk = __float22bfloat162_rn(make_float2(acc[r].x, acc[r].y));
      *(uint32*)(rowp + r * 256 + lane * 4) = *reinterpret_cast<uint32*>(&pk);
    }
    uint32 sv = (node < N) ? xb[(size_t)node * 64 + lane] : 0u;
    *(uint32*)(rowp + 2048 + lane * 4) = sv;     // self slot (r=8)
  }
  __syncthreads();

  // ---- Phase 2: 8 waves, wave = 16 cols x 32 rows (2 frags), K=1152 ----
  if (wid < 8){
    const int lr = lane & 15;
    const int lq = lane >> 4;
    f32x4 acc2[2];
    acc2[0] = (f32x4){0.f,0.f,0.f,0.f};
    acc2[1] = (f32x4){0.f,0.f,0.f,0.f};
    const short* wrow = wb + (size_t)(wid * 16 + lr) * KCAT;

    #pragma unroll 4
    for (int ks = 0; ks < 36; ++ks){
      bf16x8 b = *(const bf16x8*)(wrow + ks * 32 + lq * 8);
      #pragma unroll
      for (int m = 0; m < 2; ++m){
        bf16x8 a = *(const bf16x8*)(smem + (m * 16 + lr) * ROWP + ks * 64 + lq * 16);
        acc2[m] = __builtin_amdgcn_mfma_f32_16x16x32_bf16(a, b, acc2[m], 0, 0, 0);
      }
    }

    // Epilogue: C/D col=lane&15, row=(lane>>4)*4+v; invdeg from rs.
    #pragma unroll
    for (int m = 0; m < 2; ++m){
      int rbase = n0 + m * 16 + lq * 4;
      #pragma unroll
      for (int v = 0; v < 4; ++v){
        int ro = rbase + v;
        if (ro < N){
          int dg = rs[ro + 1] - rs[ro];
          float inv = 1.0f / (float)(dg > 0 ? dg : 1);
          out[(((size_t)ro) << 7) + wid * 16 + lr] = acc2[m][v] * inv;
        }
      }
    }
  }
}

extern "C" void kernel_launch(void* const* d_in, const int* in_sizes, int n_in,
                              void* d_out, int out_size, void* d_ws, size_t ws_size,
                              hipStream_t stream){
  const float* x  = (const float*)d_in[0];
  const int*   ei = (const int*)d_in[1];
  const int*   et = (const int*)d_in[2];
  const float* W  = (const float*)d_in[4];
  const float* W0 = (const float*)d_in[5];
  float* out = (float*)d_out;

  const int N = in_sizes[0] / NDIM;   // 50000
  const int E = in_sizes[2];          // 800000

  char* ws = (char*)d_ws;
  size_t off = 0;
  auto alloc = [&](size_t bytes)->size_t{
    size_t p = off; off = (off + bytes + 255) & ~(size_t)255; return p;
  };
  size_t o_flag = alloc(4);
  size_t o_st   = alloc((size_t)E * 4);
  size_t o_d    = alloc((size_t)E * 4);
  size_t o_deg  = alloc((size_t)N * 4);
  size_t o_rs   = alloc((size_t)(N + 1) * 4);
  size_t o_cur  = alloc((size_t)N * 4);
  size_t o_es   = alloc((size_t)E * 4);
  size_t o_wb   = alloc((size_t)NDIM * KCAT * 2);
  size_t o_xb   = alloc((size_t)N * NDIM * 2);
  (void)ws_size;

  int*  flag   = (int*)(ws + o_flag);
  int*  st     = (int*)(ws + o_st);
  int*  darr   = (int*)(ws + o_d);
  int*  deg    = (int*)(ws + o_deg);
  int*  rs     = (int*)(ws + o_rs);
  int*  cursor = (int*)(ws + o_cur);
  int*  esort  = (int*)(ws + o_es);
  short* Wbs   = (short*)(ws + o_wb);
  uint32* xb   = (uint32*)(ws + o_xb);

  const int eblk    = (E + 255) / 256;              // 3125
  const int nblk    = (N + 255) / 256;              // 196
  const int n4      = N * NDIM / 4;
  const int xblocks = (n4 + 255) / 256;             // 6250
  const int wblocks = (NDIM * KCAT + 255) / 256;    // 576

  k_prep<<<xblocks + wblocks + nblk, 256, 0, stream>>>(
      x, xb, n4, xblocks, W, W0, Wbs, wblocks, ei, flag, deg, N);
  k_norm<<<eblk, 256, 0, stream>>>(ei, et, flag, st, darr, deg, E);
  k_scan1<<<1, 1024, 0, stream>>>(deg, rs, cursor, N, E);
  k_scatter<<<eblk, 256, 0, stream>>>(st, darr, cursor, esort, E);
  k_fused<<<(N + 31) / 32, 1024, 0, stream>>>(xb, rs, esort, Wbs, out, N);
}

// Round 8
// 213.512 us; speedup vs baseline: 1.5804x; 1.5804x over previous
//
#include <hip/hip_runtime.h>
#include <hip/hip_bf16.h>
#include <cstdint>
#include <cstddef>

// RGCN layer, fused v3 + proper parallel scan:
//   out[n] = (sum_r h_r[n]@W[r] + x[n]@W0) / max(deg,1)
// k_fused: 32 nodes/block, 16 waves, LDS A[32][1160] bf16 (pad 2320B/row),
// 74.2 KB -> 2 blocks/CU (gather of one block overlaps MFMA of the other).
// Scan is the 3-dispatch scanA/scanB/scanC (round-5 proven, ~6 us total);
// round-7's single-block scan was 126 us (1 CU latency-bound) - reverted.

#define NDIM 128
#define NREL 8
#define KCAT 1152        // 9*128
#define ROWP 2320        // 2304 data bytes + 16 pad

typedef __attribute__((ext_vector_type(8))) short bf16x8;
typedef __attribute__((ext_vector_type(4))) float f32x4;
typedef unsigned int uint32;

__device__ __forceinline__ short f2bf(float f){
  __hip_bfloat16 h = __float2bfloat16(f);
  return *reinterpret_cast<short*>(&h);
}
__device__ __forceinline__ float bfl(uint32 v){ return __uint_as_float(v << 16); }
__device__ __forceinline__ float bfh(uint32 v){ return __uint_as_float(v & 0xFFFF0000u); }

// ---------- K1: x->bf16, W->Wb (transposed bf16), zero deg, detect (merged) ----------
__global__ void k_prep(const float* __restrict__ x, uint32* __restrict__ xb, int n4, int xblocks,
                       const float* __restrict__ W, const float* __restrict__ W0,
                       short* __restrict__ Wb, int wblocks,
                       const int* __restrict__ ei, int* flag, int* deg, int N){
  int b = blockIdx.x;
  if (b < xblocks){
    int i = b * 256 + threadIdx.x;
    if (i >= n4) return;
    float4 f = ((const float4*)x)[i];
    uint32 lo = ((uint32)(unsigned short)f2bf(f.x)) | (((uint32)(unsigned short)f2bf(f.y)) << 16);
    uint32 hi = ((uint32)(unsigned short)f2bf(f.z)) | (((uint32)(unsigned short)f2bf(f.w)) << 16);
    ((uint2*)xb)[i] = make_uint2(lo, hi);
  } else if (b < xblocks + wblocks){
    int i = (b - xblocks) * 256 + threadIdx.x;
    if (i >= NDIM * KCAT) return;
    int j  = i / KCAT;
    int t  = i - j * KCAT;
    int r  = t >> 7;
    int kd = t & 127;
    float v = (r < NREL) ? W[(((size_t)r * NDIM + kd) << 7) + j] : W0[((size_t)kd << 7) + j];
    Wb[i] = f2bf(v);
  } else {
    int bb = b - xblocks - wblocks;
    int i = bb * 256 + threadIdx.x;
    if (i < N) deg[i] = 0;
    if (bb == 0 && threadIdx.x < 64){
      int v = ei[2 * threadIdx.x + 1];
      unsigned long long m = __ballot(v == 0);
      if (threadIdx.x == 0) flag[0] = (m == ~0ull) ? 1 : 0;
    }
  }
}

// ---------- K2: normalize edges + degree histogram ----------
__global__ void k_norm(const int* ei, const int* et, const int* __restrict__ flag,
                       int* st, int* darr, int* deg, int E){
  int e = blockIdx.x * 256 + threadIdx.x;
  if (e >= E) return;
  int is64 = flag[0];
  int s, d, t;
  if (is64){ s = ei[2*e]; d = ei[2*(E + e)]; t = et[2*e]; }
  else     { s = ei[e];   d = ei[E + e];     t = et[e];   }
  st[e]   = s | (t << 20);
  darr[e] = d;
  atomicAdd(&deg[d], 1);
}

// ---------- K3/K4/K5: 3-dispatch exclusive scan (round-5 proven) ----------
__global__ void k_scanA(const int* deg, int* rs, int* bsum, int N){
  __shared__ int sm[256];
  int t = threadIdx.x, i = blockIdx.x * 256 + t;
  int v = (i < N) ? deg[i] : 0;
  sm[t] = v; __syncthreads();
  #pragma unroll
  for (int off = 1; off < 256; off <<= 1){
    int xv = 0; if (t >= off) xv = sm[t - off];
    __syncthreads(); sm[t] += xv; __syncthreads();
  }
  if (i < N) rs[i] = sm[t] - v;
  if (t == 255) bsum[blockIdx.x] = sm[255];
}

__global__ void k_scanB(const int* bsum, int* boff, int nblk){
  __shared__ int sm[256];
  int t = threadIdx.x;
  int v = (t < nblk) ? bsum[t] : 0;
  sm[t] = v; __syncthreads();
  #pragma unroll
  for (int off = 1; off < 256; off <<= 1){
    int xv = 0; if (t >= off) xv = sm[t - off];
    __syncthreads(); sm[t] += xv; __syncthreads();
  }
  boff[t] = sm[t] - v;
}

__global__ void k_scanC(int* rs, int* cursor, const int* boff, int N, int E){
  int i = blockIdx.x * 256 + threadIdx.x;
  if (i < N){
    int v = rs[i] + boff[blockIdx.x];
    rs[i] = v; cursor[i] = v;
  }
  if (i == 0) rs[N] = E;
}

// ---------- K6: scatter edges into CSR buckets ----------
__global__ void k_scatter(const int* st, const int* darr, int* cursor, int* esort, int E){
  int e = blockIdx.x * 256 + threadIdx.x;
  if (e >= E) return;
  int pos = atomicAdd(&cursor[darr[e]], 1);
  esort[pos] = st[e];
}

// ---------- K7: fused gather -> padded LDS -> MFMA -> out ----------
__global__ __launch_bounds__(1024) void k_fused(
    const uint32* __restrict__ xb,    // [N][64] bf16x2
    const int* __restrict__ rs,       // [N+1]
    const int* __restrict__ esort,    // [E] src|type<<20, CSR by dst
    const short* __restrict__ wb,     // [128][1152] bf16
    float* __restrict__ out, int N)
{
  __shared__ char smem[32 * ROWP];    // 74240 B -> 2 blocks/CU
  const int lane = threadIdx.x & 63;
  const int wid  = threadIdx.x >> 6;  // 0..15
  const int n0   = blockIdx.x * 32;

  // ---- Phase 1: gather, 2 nodes per wave, round-5 inner loop ----
  for (int half = 0; half < 2; ++half){
    const int row  = wid * 2 + half;  // 0..31
    const int node = n0 + row;
    float2 acc[NREL];
    #pragma unroll
    for (int r = 0; r < NREL; ++r){ acc[r].x = 0.f; acc[r].y = 0.f; }
    int beg = 0, end = 0;
    if (node < N){ beg = rs[node]; end = rs[node + 1]; }

    int i = beg;
    for (; i + 3 < end; i += 4){
      int p0 = esort[i], p1 = esort[i+1], p2 = esort[i+2], p3 = esort[i+3];
      uint32 v0 = xb[(size_t)(p0 & 0xFFFFF) * 64 + lane];
      uint32 v1 = xb[(size_t)(p1 & 0xFFFFF) * 64 + lane];
      uint32 v2 = xb[(size_t)(p2 & 0xFFFFF) * 64 + lane];
      uint32 v3 = xb[(size_t)(p3 & 0xFFFFF) * 64 + lane];
      switch (p0 >> 20){
        case 0: acc[0].x+=bfl(v0); acc[0].y+=bfh(v0); break; case 1: acc[1].x+=bfl(v0); acc[1].y+=bfh(v0); break;
        case 2: acc[2].x+=bfl(v0); acc[2].y+=bfh(v0); break; case 3: acc[3].x+=bfl(v0); acc[3].y+=bfh(v0); break;
        case 4: acc[4].x+=bfl(v0); acc[4].y+=bfh(v0); break; case 5: acc[5].x+=bfl(v0); acc[5].y+=bfh(v0); break;
        case 6: acc[6].x+=bfl(v0); acc[6].y+=bfh(v0); break; case 7: acc[7].x+=bfl(v0); acc[7].y+=bfh(v0); break;
      }
      switch (p1 >> 20){
        case 0: acc[0].x+=bfl(v1); acc[0].y+=bfh(v1); break; case 1: acc[1].x+=bfl(v1); acc[1].y+=bfh(v1); break;
        case 2: acc[2].x+=bfl(v1); acc[2].y+=bfh(v1); break; case 3: acc[3].x+=bfl(v1); acc[3].y+=bfh(v1); break;
        case 4: acc[4].x+=bfl(v1); acc[4].y+=bfh(v1); break; case 5: acc[5].x+=bfl(v1); acc[5].y+=bfh(v1); break;
        case 6: acc[6].x+=bfl(v1); acc[6].y+=bfh(v1); break; case 7: acc[7].x+=bfl(v1); acc[7].y+=bfh(v1); break;
      }
      switch (p2 >> 20){
        case 0: acc[0].x+=bfl(v2); acc[0].y+=bfh(v2); break; case 1: acc[1].x+=bfl(v2); acc[1].y+=bfh(v2); break;
        case 2: acc[2].x+=bfl(v2); acc[2].y+=bfh(v2); break; case 3: acc[3].x+=bfl(v2); acc[3].y+=bfh(v2); break;
        case 4: acc[4].x+=bfl(v2); acc[4].y+=bfh(v2); break; case 5: acc[5].x+=bfl(v2); acc[5].y+=bfh(v2); break;
        case 6: acc[6].x+=bfl(v2); acc[6].y+=bfh(v2); break; case 7: acc[7].x+=bfl(v2); acc[7].y+=bfh(v2); break;
      }
      switch (p3 >> 20){
        case 0: acc[0].x+=bfl(v3); acc[0].y+=bfh(v3); break; case 1: acc[1].x+=bfl(v3); acc[1].y+=bfh(v3); break;
        case 2: acc[2].x+=bfl(v3); acc[2].y+=bfh(v3); break; case 3: acc[3].x+=bfl(v3); acc[3].y+=bfh(v3); break;
        case 4: acc[4].x+=bfl(v3); acc[4].y+=bfh(v3); break; case 5: acc[5].x+=bfl(v3); acc[5].y+=bfh(v3); break;
        case 6: acc[6].x+=bfl(v3); acc[6].y+=bfh(v3); break; case 7: acc[7].x+=bfl(v3); acc[7].y+=bfh(v3); break;
      }
    }
    for (; i < end; ++i){
      int p = esort[i];
      uint32 v = xb[(size_t)(p & 0xFFFFF) * 64 + lane];
      switch (p >> 20){
        case 0: acc[0].x+=bfl(v); acc[0].y+=bfh(v); break; case 1: acc[1].x+=bfl(v); acc[1].y+=bfh(v); break;
        case 2: acc[2].x+=bfl(v); acc[2].y+=bfh(v); break; case 3: acc[3].x+=bfl(v); acc[3].y+=bfh(v); break;
        case 4: acc[4].x+=bfl(v); acc[4].y+=bfh(v); break; case 5: acc[5].x+=bfl(v); acc[5].y+=bfh(v); break;
        case 6: acc[6].x+=bfl(v); acc[6].y+=bfh(v); break; case 7: acc[7].x+=bfl(v); acc[7].y+=bfh(v); break;
      }
    }

    char* rowp = smem + row * ROWP;
    #pragma unroll
    for (int r = 0; r < NREL; ++r){
      __hip_bfloat162 pk = __float22bfloat162_rn(make_float2(acc[r].x, acc[r].y));
      *(uint32*)(rowp + r * 256 + lane * 4) = *reinterpret_cast<uint32*>(&pk);
    }
    uint32 sv = (node < N) ? xb[(size_t)node * 64 + lane] : 0u;
    *(uint32*)(rowp + 2048 + lane * 4) = sv;     // self slot (r=8)
  }
  __syncthreads();

  // ---- Phase 2: 8 waves, wave = 16 cols x 32 rows (2 frags), K=1152 ----
  if (wid < 8){
    const int lr = lane & 15;
    const int lq = lane >> 4;
    f32x4 acc2[2];
    acc2[0] = (f32x4){0.f,0.f,0.f,0.f};
    acc2[1] = (f32x4){0.f,0.f,0.f,0.f};
    const short* wrow = wb + (size_t)(wid * 16 + lr) * KCAT;

    #pragma unroll 4
    for (int ks = 0; ks < 36; ++ks){
      bf16x8 b = *(const bf16x8*)(wrow + ks * 32 + lq * 8);
      #pragma unroll
      for (int m = 0; m < 2; ++m){
        bf16x8 a = *(const bf16x8*)(smem + (m * 16 + lr) * ROWP + ks * 64 + lq * 16);
        acc2[m] = __builtin_amdgcn_mfma_f32_16x16x32_bf16(a, b, acc2[m], 0, 0, 0);
      }
    }

    // Epilogue: C/D col=lane&15, row=(lane>>4)*4+v; invdeg from rs.
    #pragma unroll
    for (int m = 0; m < 2; ++m){
      int rbase = n0 + m * 16 + lq * 4;
      #pragma unroll
      for (int v = 0; v < 4; ++v){
        int ro = rbase + v;
        if (ro < N){
          int dg = rs[ro + 1] - rs[ro];
          float inv = 1.0f / (float)(dg > 0 ? dg : 1);
          out[(((size_t)ro) << 7) + wid * 16 + lr] = acc2[m][v] * inv;
        }
      }
    }
  }
}

extern "C" void kernel_launch(void* const* d_in, const int* in_sizes, int n_in,
                              void* d_out, int out_size, void* d_ws, size_t ws_size,
                              hipStream_t stream){
  const float* x  = (const float*)d_in[0];
  const int*   ei = (const int*)d_in[1];
  const int*   et = (const int*)d_in[2];
  const float* W  = (const float*)d_in[4];
  const float* W0 = (const float*)d_in[5];
  float* out = (float*)d_out;

  const int N = in_sizes[0] / NDIM;   // 50000
  const int E = in_sizes[2];          // 800000

  char* ws = (char*)d_ws;
  size_t off = 0;
  auto alloc = [&](size_t bytes)->size_t{
    size_t p = off; off = (off + bytes + 255) & ~(size_t)255; return p;
  };
  size_t o_flag = alloc(4);
  size_t o_st   = alloc((size_t)E * 4);
  size_t o_d    = alloc((size_t)E * 4);
  size_t o_deg  = alloc((size_t)N * 4);
  size_t o_rs   = alloc((size_t)(N + 1) * 4);
  size_t o_cur  = alloc((size_t)N * 4);
  size_t o_bs   = alloc(256 * 4);
  size_t o_bo   = alloc(256 * 4);
  size_t o_es   = alloc((size_t)E * 4);
  size_t o_wb   = alloc((size_t)NDIM * KCAT * 2);
  size_t o_xb   = alloc((size_t)N * NDIM * 2);
  (void)ws_size;

  int*  flag   = (int*)(ws + o_flag);
  int*  st     = (int*)(ws + o_st);
  int*  darr   = (int*)(ws + o_d);
  int*  deg    = (int*)(ws + o_deg);
  int*  rs     = (int*)(ws + o_rs);
  int*  cursor = (int*)(ws + o_cur);
  int*  bsum   = (int*)(ws + o_bs);
  int*  boff   = (int*)(ws + o_bo);
  int*  esort  = (int*)(ws + o_es);
  short* Wbs   = (short*)(ws + o_wb);
  uint32* xb   = (uint32*)(ws + o_xb);

  const int eblk    = (E + 255) / 256;              // 3125
  const int nblk    = (N + 255) / 256;              // 196
  const int n4      = N * NDIM / 4;
  const int xblocks = (n4 + 255) / 256;             // 6250
  const int wblocks = (NDIM * KCAT + 255) / 256;    // 576

  k_prep<<<xblocks + wblocks + nblk, 256, 0, stream>>>(
      x, xb, n4, xblocks, W, W0, Wbs, wblocks, ei, flag, deg, N);
  k_norm<<<eblk, 256, 0, stream>>>(ei, et, flag, st, darr, deg, E);
  k_scanA<<<nblk, 256, 0, stream>>>(deg, rs, bsum, N);
  k_scanB<<<1, 256, 0, stream>>>(bsum, boff, nblk);
  k_scanC<<<nblk, 256, 0, stream>>>(rs, cursor, boff, N, E);
  k_scatter<<<eblk, 256, 0, stream>>>(st, darr, cursor, esort, E);
  k_fused<<<(N + 31) / 32, 1024, 0, stream>>>(xb, rs, esort, Wbs, out, N);
}

// Round 9
// 125.865 us; speedup vs baseline: 2.6810x; 1.6964x over previous
//
#include <hip/hip_runtime.h>
#include <hip/hip_bf16.h>
#include <cstdint>
#include <cstddef>

// RGCN layer: out = (x@W0 + sum_r h_r@W[r]) / max(deg,1)
// Split structure (round-5 proven agg+gemm) + atomic-free edge grouping:
//   k_prep:     x->bf16, W->Wb^T bf16, zero coarse_cnt, int64 detect
//   k_hist:     LDS hist over 196 coarse buckets (dst>>8) + 38K reserve atomics
//   k_base:     scan 196 coarse counts
//   k_cscatter: LDS-cursor scatter kv -> coarse-grouped ckv
//   k_fine:     per-bucket LDS hist/scan over dst&255 -> rs[] + final esort
//   k_agg:      1 wave/node CSR gather (bf16) -> h_cat[n][1152] + invdeg
//   k_gemm2:    [N,1152]@[1152,128] m97-structure MFMA GEMM
// No scattered device atomics anywhere (the hidden ~93 us of rounds 3-8).

#define NDIM 128
#define NREL 8
#define KCAT 1152        // 9*128
#define COARSE 196       // dst>>8 buckets, dst < 50176
#define EPB 4096         // edges per hist/cscatter block

typedef __attribute__((ext_vector_type(8))) short bf16x8;
typedef __attribute__((ext_vector_type(4))) float f32x4;
typedef unsigned int uint32;

__device__ __forceinline__ short f2bf(float f){
  __hip_bfloat16 h = __float2bfloat16(f);
  return *reinterpret_cast<short*>(&h);
}
__device__ __forceinline__ float bfl(uint32 v){ return __uint_as_float(v << 16); }
__device__ __forceinline__ float bfh(uint32 v){ return __uint_as_float(v & 0xFFFF0000u); }

__device__ __forceinline__ void gload_lds16(const void* g, void* l){
  __builtin_amdgcn_global_load_lds(
      (const __attribute__((address_space(1))) unsigned int*)g,
      (__attribute__((address_space(3))) unsigned int*)l, 16, 0, 0);
}

// ---------- K1: casts + zero coarse_cnt + detect ----------
__global__ void k_prep(const float* __restrict__ x, uint32* __restrict__ xb, int n4, int xblocks,
                       const float* __restrict__ W, const float* __restrict__ W0,
                       short* __restrict__ Wb, int wblocks,
                       const int* __restrict__ ei, int* flag, int* coarse_cnt){
  int b = blockIdx.x;
  if (b < xblocks){
    int i = b * 256 + threadIdx.x;
    if (i >= n4) return;
    float4 f = ((const float4*)x)[i];
    uint32 lo = ((uint32)(unsigned short)f2bf(f.x)) | (((uint32)(unsigned short)f2bf(f.y)) << 16);
    uint32 hi = ((uint32)(unsigned short)f2bf(f.z)) | (((uint32)(unsigned short)f2bf(f.w)) << 16);
    ((uint2*)xb)[i] = make_uint2(lo, hi);
  } else if (b < xblocks + wblocks){
    int i = (b - xblocks) * 256 + threadIdx.x;
    if (i >= NDIM * KCAT) return;
    int j  = i / KCAT;
    int t  = i - j * KCAT;
    int r  = t >> 7;
    int kd = t & 127;
    float v = (r < NREL) ? W[(((size_t)r * NDIM + kd) << 7) + j] : W0[((size_t)kd << 7) + j];
    Wb[i] = f2bf(v);
  } else {
    if (threadIdx.x < COARSE) coarse_cnt[threadIdx.x] = 0;
    if (threadIdx.x < 64){
      int v = ei[2 * threadIdx.x + 1];
      unsigned long long m = __ballot(v == 0);
      if (threadIdx.x == 0) flag[0] = (m == ~0ull) ? 1 : 0;
    }
  }
}

// ---------- K2: decode + pack + coarse LDS hist + block reservations ----------
__global__ __launch_bounds__(1024) void k_hist(
    const int* __restrict__ ei, const int* __restrict__ et, const int* __restrict__ flag,
    uint32* __restrict__ kv, unsigned char* __restrict__ ctmp,
    int* __restrict__ coarse_cnt, int* __restrict__ blockRes, int E){
  __shared__ int h[COARSE];
  const int b = blockIdx.x;
  for (int i = threadIdx.x; i < COARSE; i += 1024) h[i] = 0;
  __syncthreads();
  const int is64 = flag[0];
  const int e0 = b * EPB;
  for (int i = threadIdx.x; i < EPB; i += 1024){
    int e = e0 + i;
    if (e < E){
      int s, d, t;
      if (is64){ s = ei[2*e]; d = ei[2*(E + e)]; t = et[2*e]; }
      else     { s = ei[e];   d = ei[E + e];     t = et[e];   }
      int c = d >> 8;
      kv[e]   = (uint32)s | ((uint32)t << 16) | ((uint32)(d & 255) << 19);
      ctmp[e] = (unsigned char)c;
      atomicAdd(&h[c], 1);                       // LDS atomic
    }
  }
  __syncthreads();
  for (int c = threadIdx.x; c < COARSE; c += 1024){
    int cnt = h[c];
    int res = 0;
    if (cnt > 0) res = atomicAdd(&coarse_cnt[c], cnt);   // 196/block, spread
    blockRes[b * COARSE + c] = res;
  }
}

// ---------- K3: scan coarse counts -> base[COARSE+1] ----------
__global__ void k_base(const int* __restrict__ coarse_cnt, int* __restrict__ base){
  __shared__ int sm[256];
  int t = threadIdx.x;
  int v = (t < COARSE) ? coarse_cnt[t] : 0;
  sm[t] = v; __syncthreads();
  #pragma unroll
  for (int off = 1; off < 256; off <<= 1){
    int xv = 0; if (t >= off) xv = sm[t - off];
    __syncthreads(); sm[t] += xv; __syncthreads();
  }
  if (t <= COARSE) base[t] = sm[t] - v;   // exclusive; base[COARSE] = E
}

// ---------- K4: scatter kv into coarse-grouped order (LDS cursors) ----------
__global__ __launch_bounds__(1024) void k_cscatter(
    const uint32* __restrict__ kv, const unsigned char* __restrict__ ctmp,
    const int* __restrict__ base, const int* __restrict__ blockRes,
    uint32* __restrict__ ckv, int E){
  __shared__ int cur[COARSE];
  const int b = blockIdx.x;
  for (int c = threadIdx.x; c < COARSE; c += 1024)
    cur[c] = base[c] + blockRes[b * COARSE + c];
  __syncthreads();
  const int e0 = b * EPB;
  for (int i = threadIdx.x; i < EPB; i += 1024){
    int e = e0 + i;
    if (e < E){
      uint32 v = kv[e];
      int c = ctmp[e];
      int pos = atomicAdd(&cur[c], 1);           // LDS atomic
      ckv[pos] = v;
    }
  }
}

// ---------- K5: per-bucket fine grouping by dst&255 -> rs[], esort ----------
__global__ __launch_bounds__(1024) void k_fine(
    const uint32* __restrict__ ckv, const int* __restrict__ base,
    uint32* __restrict__ esort, int* __restrict__ rs, int N){
  __shared__ int h[256];
  __shared__ int cur[256];
  const int c  = blockIdx.x;
  const int lo = base[c], hi = base[c + 1];
  const int t  = threadIdx.x;
  if (t < 256) h[t] = 0;
  __syncthreads();
  for (int i = lo + t; i < hi; i += 1024)
    atomicAdd(&h[(ckv[i] >> 19) & 255], 1);      // LDS atomic
  __syncthreads();
  int v = (t < 256) ? h[t] : 0;
  __syncthreads();
  for (int off = 1; off < 256; off <<= 1){
    int xv = 0;
    if (t < 256 && t >= off) xv = h[t - off];
    __syncthreads();
    if (t < 256) h[t] += xv;
    __syncthreads();
  }
  if (t < 256){
    int excl = h[t] - v;                          // exclusive prefix
    cur[t] = lo + excl;
    int idx = c * 256 + t;
    if (idx <= N) rs[idx] = lo + excl;            // dense CSR bounds
  }
  __syncthreads();
  for (int i = lo + t; i < hi; i += 1024){
    uint32 v2 = ckv[i];
    int pos = atomicAdd(&cur[(v2 >> 19) & 255], 1);  // LDS atomic
    esort[pos] = v2;
  }
}

// ---------- K6: aggregation (round-5 proven; masks for new packing) ----------
// esort: src = p & 0xFFFF, type = (p>>16)&7
__global__ __launch_bounds__(256) void k_agg(const uint32* __restrict__ xb,
                                             const int* __restrict__ rs,
                                             const uint32* __restrict__ esort,
                                             uint32* __restrict__ hcat,
                                             float* __restrict__ invdeg, int N){
  int wave = threadIdx.x >> 6;
  int lane = threadIdx.x & 63;
  int n = blockIdx.x * 4 + wave;
  if (n >= N) return;
  int beg = rs[n], end = rs[n + 1];
  float2 acc[NREL];
  #pragma unroll
  for (int r = 0; r < NREL; ++r){ acc[r].x = 0.f; acc[r].y = 0.f; }

  int i = beg;
  for (; i + 3 < end; i += 4){
    uint32 p0 = esort[i], p1 = esort[i+1], p2 = esort[i+2], p3 = esort[i+3];
    uint32 v0 = xb[(size_t)(p0 & 0xFFFF) * 64 + lane];
    uint32 v1 = xb[(size_t)(p1 & 0xFFFF) * 64 + lane];
    uint32 v2 = xb[(size_t)(p2 & 0xFFFF) * 64 + lane];
    uint32 v3 = xb[(size_t)(p3 & 0xFFFF) * 64 + lane];
    switch ((p0 >> 16) & 7){
      case 0: acc[0].x+=bfl(v0); acc[0].y+=bfh(v0); break; case 1: acc[1].x+=bfl(v0); acc[1].y+=bfh(v0); break;
      case 2: acc[2].x+=bfl(v0); acc[2].y+=bfh(v0); break; case 3: acc[3].x+=bfl(v0); acc[3].y+=bfh(v0); break;
      case 4: acc[4].x+=bfl(v0); acc[4].y+=bfh(v0); break; case 5: acc[5].x+=bfl(v0); acc[5].y+=bfh(v0); break;
      case 6: acc[6].x+=bfl(v0); acc[6].y+=bfh(v0); break; case 7: acc[7].x+=bfl(v0); acc[7].y+=bfh(v0); break;
    }
    switch ((p1 >> 16) & 7){
      case 0: acc[0].x+=bfl(v1); acc[0].y+=bfh(v1); break; case 1: acc[1].x+=bfl(v1); acc[1].y+=bfh(v1); break;
      case 2: acc[2].x+=bfl(v1); acc[2].y+=bfh(v1); break; case 3: acc[3].x+=bfl(v1); acc[3].y+=bfh(v1); break;
      case 4: acc[4].x+=bfl(v1); acc[4].y+=bfh(v1); break; case 5: acc[5].x+=bfl(v1); acc[5].y+=bfh(v1); break;
      case 6: acc[6].x+=bfl(v1); acc[6].y+=bfh(v1); break; case 7: acc[7].x+=bfl(v1); acc[7].y+=bfh(v1); break;
    }
    switch ((p2 >> 16) & 7){
      case 0: acc[0].x+=bfl(v2); acc[0].y+=bfh(v2); break; case 1: acc[1].x+=bfl(v2); acc[1].y+=bfh(v2); break;
      case 2: acc[2].x+=bfl(v2); acc[2].y+=bfh(v2); break; case 3: acc[3].x+=bfl(v2); acc[3].y+=bfh(v2); break;
      case 4: acc[4].x+=bfl(v2); acc[4].y+=bfh(v2); break; case 5: acc[5].x+=bfl(v2); acc[5].y+=bfh(v2); break;
      case 6: acc[6].x+=bfl(v2); acc[6].y+=bfh(v2); break; case 7: acc[7].x+=bfl(v2); acc[7].y+=bfh(v2); break;
    }
    switch ((p3 >> 16) & 7){
      case 0: acc[0].x+=bfl(v3); acc[0].y+=bfh(v3); break; case 1: acc[1].x+=bfl(v3); acc[1].y+=bfh(v3); break;
      case 2: acc[2].x+=bfl(v3); acc[2].y+=bfh(v3); break; case 3: acc[3].x+=bfl(v3); acc[3].y+=bfh(v3); break;
      case 4: acc[4].x+=bfl(v3); acc[4].y+=bfh(v3); break; case 5: acc[5].x+=bfl(v3); acc[5].y+=bfh(v3); break;
      case 6: acc[6].x+=bfl(v3); acc[6].y+=bfh(v3); break; case 7: acc[7].x+=bfl(v3); acc[7].y+=bfh(v3); break;
    }
  }
  for (; i < end; ++i){
    uint32 p = esort[i];
    uint32 v = xb[(size_t)(p & 0xFFFF) * 64 + lane];
    switch ((p >> 16) & 7){
      case 0: acc[0].x+=bfl(v); acc[0].y+=bfh(v); break; case 1: acc[1].x+=bfl(v); acc[1].y+=bfh(v); break;
      case 2: acc[2].x+=bfl(v); acc[2].y+=bfh(v); break; case 3: acc[3].x+=bfl(v); acc[3].y+=bfh(v); break;
      case 4: acc[4].x+=bfl(v); acc[4].y+=bfh(v); break; case 5: acc[5].x+=bfl(v); acc[5].y+=bfh(v); break;
      case 6: acc[6].x+=bfl(v); acc[6].y+=bfh(v); break; case 7: acc[7].x+=bfl(v); acc[7].y+=bfh(v); break;
    }
  }

  size_t b2 = (size_t)n * (KCAT / 2);
  #pragma unroll
  for (int r = 0; r < NREL; ++r){
    __hip_bfloat162 pk = __float22bfloat162_rn(make_float2(acc[r].x, acc[r].y));
    hcat[b2 + r * 64 + lane] = *reinterpret_cast<uint32*>(&pk);
  }
  hcat[b2 + 512 + lane] = xb[(size_t)n * 64 + lane];
  if (lane == 0){
    int d = end - beg;
    invdeg[n] = 1.0f / (float)(d > 0 ? d : 1);
  }
}

// ---------- K7: GEMM (round-5 verbatim) ----------
__global__ __launch_bounds__(256) void k_gemm2(
    const short* __restrict__ acat, const short* __restrict__ wb,
    const float* __restrict__ invdeg, float* __restrict__ out, int N)
{
  __shared__ char smem[49152];
  char* As0 = smem;
  char* As1 = smem + 8192;
  char* Bs0 = smem + 16384;
  char* Bs1 = smem + 32768;

  const int tid  = threadIdx.x;
  const int lane = tid & 63;
  const int wid  = tid >> 6;
  const int wr   = wid >> 1;
  const int wc   = wid & 1;
  const int n0   = blockIdx.x * 64;
  const int lr   = lane & 15;
  const int lq   = lane >> 4;

  f32x4 acc[2][4];
  #pragma unroll
  for (int m = 0; m < 2; ++m)
    #pragma unroll
    for (int p = 0; p < 4; ++p)
      acc[m][p] = (f32x4){0.f, 0.f, 0.f, 0.f};

  const int srow = tid >> 3;
  const int scs  = tid & 7;

  auto STAGE = [&](char* Ab, char* Bb, int ks){
    const short* ab = acat + (size_t)n0 * KCAT + ks * 64;
    #pragma unroll
    for (int q = 0; q < 2; ++q){
      int row = q * 32 + srow;
      const short* src = ab + (size_t)row * KCAT + ((scs ^ (row & 7)) << 3);
      gload_lds16(src, Ab + q * 4096 + (wid << 10));
    }
    const short* bb = wb + ks * 64;
    #pragma unroll
    for (int q = 0; q < 4; ++q){
      int j = q * 32 + srow;
      const short* src = bb + (size_t)j * KCAT + ((scs ^ (j & 7)) << 3);
      gload_lds16(src, Bb + q * 4096 + (wid << 10));
    }
  };

  auto COMPUTE = [&](const char* Ab, const char* Bb){
    bf16x8 a[2][2], b[2][4];
    #pragma unroll
    for (int kk = 0; kk < 2; ++kk){
      #pragma unroll
      for (int m = 0; m < 2; ++m){
        int row = wr * 32 + m * 16 + lr;
        int c   = kk * 4 + lq;
        a[kk][m] = *(const bf16x8*)(Ab + row * 128 + ((c ^ (row & 7)) << 4));
      }
      #pragma unroll
      for (int p = 0; p < 4; ++p){
        int j = wc * 64 + p * 16 + lr;
        int c = kk * 4 + lq;
        b[kk][p] = *(const bf16x8*)(Bb + j * 128 + ((c ^ (j & 7)) << 4));
      }
    }
    #pragma unroll
    for (int kk = 0; kk < 2; ++kk)
      #pragma unroll
      for (int m = 0; m < 2; ++m)
        #pragma unroll
        for (int p = 0; p < 4; ++p)
          acc[m][p] = __builtin_amdgcn_mfma_f32_16x16x32_bf16(a[kk][m], b[kk][p], acc[m][p], 0, 0, 0);
  };

  STAGE(As0, Bs0, 0);
  __syncthreads();
  for (int ks = 0; ks < 18; ks += 2){
    STAGE(As1, Bs1, ks + 1);
    COMPUTE(As0, Bs0);
    __syncthreads();
    if (ks + 2 < 18) STAGE(As0, Bs0, ks + 2);
    COMPUTE(As1, Bs1);
    __syncthreads();
  }

  #pragma unroll
  for (int m = 0; m < 2; ++m){
    int rbase = n0 + wr * 32 + m * 16 + lq * 4;
    #pragma unroll
    for (int v = 0; v < 4; ++v){
      int ro = rbase + v;
      if (ro < N){
        float inv = invdeg[ro];
        #pragma unroll
        for (int p = 0; p < 4; ++p)
          out[(((size_t)ro) << 7) + wc * 64 + p * 16 + lr] = acc[m][p][v] * inv;
      }
    }
  }
}

extern "C" void kernel_launch(void* const* d_in, const int* in_sizes, int n_in,
                              void* d_out, int out_size, void* d_ws, size_t ws_size,
                              hipStream_t stream){
  const float* x  = (const float*)d_in[0];
  const int*   ei = (const int*)d_in[1];
  const int*   et = (const int*)d_in[2];
  const float* W  = (const float*)d_in[4];
  const float* W0 = (const float*)d_in[5];
  float* out = (float*)d_out;

  const int N = in_sizes[0] / NDIM;   // 50000
  const int E = in_sizes[2];          // 800000
  const int Npad = N + 64;
  const int nblkE = (E + EPB - 1) / EPB;   // 196

  char* ws = (char*)d_ws;
  size_t off = 0;
  auto alloc = [&](size_t bytes)->size_t{
    size_t p = off; off = (off + bytes + 255) & ~(size_t)255; return p;
  };
  size_t o_flag = alloc(4);
  size_t o_kv   = alloc((size_t)E * 4);
  size_t o_ct   = alloc((size_t)E);
  size_t o_ckv  = alloc((size_t)E * 4);
  size_t o_es   = alloc((size_t)E * 4);
  size_t o_cc   = alloc(COARSE * 4);
  size_t o_base = alloc((COARSE + 2) * 4);
  size_t o_br   = alloc((size_t)nblkE * COARSE * 4);
  size_t o_rs   = alloc((size_t)(N + 1) * 4);
  size_t o_inv  = alloc((size_t)N * 4);
  size_t o_h    = alloc((size_t)Npad * KCAT * 2);
  size_t o_wb   = alloc((size_t)NDIM * KCAT * 2);
  size_t o_xb   = alloc((size_t)N * NDIM * 2);
  (void)ws_size;

  int*  flag   = (int*)(ws + o_flag);
  uint32* kv   = (uint32*)(ws + o_kv);
  unsigned char* ctmp = (unsigned char*)(ws + o_ct);
  uint32* ckv  = (uint32*)(ws + o_ckv);
  uint32* esort= (uint32*)(ws + o_es);
  int*  ccnt   = (int*)(ws + o_cc);
  int*  base   = (int*)(ws + o_base);
  int*  bres   = (int*)(ws + o_br);
  int*  rs     = (int*)(ws + o_rs);
  float* invdeg= (float*)(ws + o_inv);
  uint32* hcat = (uint32*)(ws + o_h);
  short* acat  = (short*)(ws + o_h);
  short* Wbs   = (short*)(ws + o_wb);
  uint32* xb   = (uint32*)(ws + o_xb);

  const int n4      = N * NDIM / 4;
  const int xblocks = (n4 + 255) / 256;             // 6250
  const int wblocks = (NDIM * KCAT + 255) / 256;    // 576

  k_prep<<<xblocks + wblocks + 1, 256, 0, stream>>>(
      x, xb, n4, xblocks, W, W0, Wbs, wblocks, ei, flag, ccnt);
  k_hist<<<nblkE, 1024, 0, stream>>>(ei, et, flag, kv, ctmp, ccnt, bres, E);
  k_base<<<1, 256, 0, stream>>>(ccnt, base);
  k_cscatter<<<nblkE, 1024, 0, stream>>>(kv, ctmp, base, bres, ckv, E);
  k_fine<<<COARSE, 1024, 0, stream>>>(ckv, base, esort, rs, N);
  k_agg<<<(N + 3) / 4, 256, 0, stream>>>(xb, rs, esort, hcat, invdeg, N);
  k_gemm2<<<(N + 63) / 64, 256, 0, stream>>>(acat, Wbs, invdeg, out, N);
}